// Round 1
// baseline (1053.839 us; speedup 1.0000x reference)
//
#include <hip/hip_runtime.h>

// DegreeWiseLinear: out[n,m,d] = sum_c x[n, m+1, c] * W[deg(m), c, d], m in [0,24)
// out[n, 24..34, d] = 0.   N=65536, C_in=C_out=64, x has 25 orders, out has 35.
// deg(m): [0,3)->0, [3,8)->1, [8,15)->2, [15,24)->3   (repeats 3,5,7,9)

constexpr int ORD_IN  = 25;
constexpr int ORD_OUT = 35;
constexpr int CCH     = 64;
constexpr int ROWS    = 128;   // rows (n) per block
constexpr int NREG    = 2;     // rows per lane (64 lanes * 2 = 128)

__global__ __launch_bounds__(256, 4)
void dwl_main(const float* __restrict__ x, const float* __restrict__ w,
              float* __restrict__ out) {
    const int  m   = blockIdx.x;                 // order 0..23
    const long n0  = (long)blockIdx.y * ROWS;    // base row
    const int  deg = (m >= 3) + (m >= 8) + (m >= 15);
    const int  t    = threadIdx.x;
    const int  lane = t & 63;
    const int  wid  = t >> 6;                    // wave id -> d-group
    const int  d0   = wid * 16;

    __shared__ float ws[64][64];                 // W[deg] : [c][d], 16 KiB

    // ---- stage W (whole block, coalesced float4) ----
    {
        const float4* src = reinterpret_cast<const float4*>(w + deg * (CCH * CCH));
        float4*       dst = reinterpret_cast<float4*>(&ws[0][0]);
#pragma unroll
        for (int i = 0; i < 4; ++i) dst[t + 256 * i] = src[t + 256 * i];
    }
    __syncthreads();

    // ---- per-lane x rows (2 rows, contiguous) ----
    const float* xrow0 = x + (n0 + 2 * lane) * (long)(ORD_IN * CCH) + (m + 1) * CCH;
    const float* xrow1 = xrow0 + ORD_IN * CCH;

    float acc[NREG][16];
#pragma unroll
    for (int r = 0; r < NREG; ++r)
#pragma unroll
        for (int j = 0; j < 16; ++j) acc[r][j] = 0.f;

    // double-buffered c-chunks of 8: xc[buf][row][8]
    float xc[2][NREG][8];

    // preload chunk 0
    {
        *reinterpret_cast<float4*>(&xc[0][0][0]) = reinterpret_cast<const float4*>(xrow0)[0];
        *reinterpret_cast<float4*>(&xc[0][0][4]) = reinterpret_cast<const float4*>(xrow0)[1];
        *reinterpret_cast<float4*>(&xc[0][1][0]) = reinterpret_cast<const float4*>(xrow1)[0];
        *reinterpret_cast<float4*>(&xc[0][1][4]) = reinterpret_cast<const float4*>(xrow1)[1];
    }

#pragma unroll
    for (int ch = 0; ch < 8; ++ch) {
        const int b = ch & 1;
        // prefetch next chunk
        if (ch < 7) {
            const int nb = (ch + 1) & 1;
            const float* p0 = xrow0 + (ch + 1) * 8;
            const float* p1 = xrow1 + (ch + 1) * 8;
            *reinterpret_cast<float4*>(&xc[nb][0][0]) = reinterpret_cast<const float4*>(p0)[0];
            *reinterpret_cast<float4*>(&xc[nb][0][4]) = reinterpret_cast<const float4*>(p0)[1];
            *reinterpret_cast<float4*>(&xc[nb][1][0]) = reinterpret_cast<const float4*>(p1)[0];
            *reinterpret_cast<float4*>(&xc[nb][1][4]) = reinterpret_cast<const float4*>(p1)[1];
        }
#pragma unroll
        for (int cc = 0; cc < 8; ++cc) {
            const int c = ch * 8 + cc;
            // wave-uniform W row slice: broadcast LDS reads (conflict-free)
            float wv[16];
            *reinterpret_cast<float4*>(&wv[0])  = *reinterpret_cast<const float4*>(&ws[c][d0 + 0]);
            *reinterpret_cast<float4*>(&wv[4])  = *reinterpret_cast<const float4*>(&ws[c][d0 + 4]);
            *reinterpret_cast<float4*>(&wv[8])  = *reinterpret_cast<const float4*>(&ws[c][d0 + 8]);
            *reinterpret_cast<float4*>(&wv[12]) = *reinterpret_cast<const float4*>(&ws[c][d0 + 12]);
#pragma unroll
            for (int r = 0; r < NREG; ++r) {
                const float xv = xc[b][r][cc];
#pragma unroll
                for (int j = 0; j < 16; ++j)
                    acc[r][j] = fmaf(xv, wv[j], acc[r][j]);
            }
        }
    }

    // ---- store: each lane writes 2 rows x 16 d (64B-aligned full segments) ----
#pragma unroll
    for (int r = 0; r < NREG; ++r) {
        float* orow = out + (n0 + 2 * lane + r) * (long)(ORD_OUT * CCH) + m * CCH + d0;
#pragma unroll
        for (int j = 0; j < 4; ++j)
            *reinterpret_cast<float4*>(orow + 4 * j) =
                make_float4(acc[r][4 * j + 0], acc[r][4 * j + 1],
                            acc[r][4 * j + 2], acc[r][4 * j + 3]);
    }

    // ---- fused zero-pad: blocks m<11 zero order 24+m for this row tile ----
    if (m < 11) {
        const int om = 24 + m;
        const float4 z = make_float4(0.f, 0.f, 0.f, 0.f);
#pragma unroll
        for (int i = 0; i < 8; ++i) {
            const int idx = t + i * 256;        // 0..2047 = 128 rows * 16 float4
            const int row = idx >> 4;
            const int q   = idx & 15;
            reinterpret_cast<float4*>(out + (n0 + row) * (long)(ORD_OUT * CCH) + om * CCH)[q] = z;
        }
    }
}

extern "C" void kernel_launch(void* const* d_in, const int* in_sizes, int n_in,
                              void* d_out, int out_size, void* d_ws, size_t ws_size,
                              hipStream_t stream) {
    const float* x   = (const float*)d_in[0];   // (65536, 25, 64) fp32
    const float* wgt = (const float*)d_in[1];   // (4, 64, 64) fp32
    float*       out = (float*)d_out;           // (65536, 35, 64) fp32

    dim3 grid(24, 65536 / ROWS);                // (m, n-tile)
    dwl_main<<<grid, 256, 0, stream>>>(x, wgt, out);
}